// Round 13
// baseline (260.247 us; speedup 1.0000x reference)
//
#include <hip/hip_runtime.h>
#include <hip/hip_bf16.h>

#define TB 2048
#define CC 1024
#define NH 16
#define HD 64
#define NB 4
#define BHX (NB*NH)    // 64
#define BTX (NB*TB)    // 8192

typedef __attribute__((ext_vector_type(8))) short bf16x8;
typedef __attribute__((ext_vector_type(4))) float f32x4;
typedef __attribute__((ext_vector_type(4))) unsigned short us4;

__device__ __forceinline__ unsigned short bfb(float f) {
  __hip_bfloat16 h = __float2bfloat16(f);
  return __builtin_bit_cast(unsigned short, h);
}
__device__ __forceinline__ float fexp2(float x) {
  return __builtin_amdgcn_exp2f(x);   // v_exp_f32 (2^x)
}
template <int CTRL>
__device__ __forceinline__ float dppf(float x) {
  int r = __builtin_amdgcn_update_dpp(0, __builtin_bit_cast(int, x), CTRL, 0xf, 0xf, false);
  return __builtin_bit_cast(float, r);
}

__device__ __forceinline__ void gld_lds16(const void* g, void* l) {
  __builtin_amdgcn_global_load_lds(
      (const __attribute__((address_space(1))) unsigned*)g,
      (__attribute__((address_space(3))) unsigned*)l, 16, 0, 0);
}

__global__ void cvt_f32_bf16(const float* __restrict__ src,
                             unsigned short* __restrict__ dst, int n4) {
  int i = blockIdx.x * blockDim.x + threadIdx.x;
  if (i >= n4) return;
  f32x4 v = ((const f32x4*)src)[i];
  us4 o;
#pragma unroll
  for (int j = 0; j < 4; j++) o[j] = bfb(v[j]);
  ((us4*)dst)[i] = o;
}

// 4 weight matrices (1024x1024 f32 each) -> bf16, one launch.
__global__ void cvt_w4(const float* __restrict__ s0, const float* __restrict__ s1,
                       const float* __restrict__ s2, const float* __restrict__ s3,
                       unsigned short* __restrict__ d0, unsigned short* __restrict__ d1,
                       unsigned short* __restrict__ d2, unsigned short* __restrict__ d3) {
  int y = blockIdx.y;
  const float* s = y == 0 ? s0 : y == 1 ? s1 : y == 2 ? s2 : s3;
  unsigned short* d = y == 0 ? d0 : y == 1 ? d1 : y == 2 ? d2 : d3;
  int i = blockIdx.x * 256 + threadIdx.x;
  f32x4 v = ((const f32x4*)s)[i];
  us4 o;
#pragma unroll
  for (int j = 0; j < 4; j++) o[j] = bfb(v[j]);
  ((us4*)d)[i] = o;
}

__global__ void prep_bias(const float* __restrict__ bq, const float* __restrict__ bk,
                          const float* __restrict__ bv, float* __restrict__ out) {
  int i = blockIdx.x * 256 + threadIdx.x;   // grid 12*256 = 3072
  float v = i < 1024 ? bq[i] : i < 2048 ? bk[i - 1024] : bv[i - 2048];
  out[i] = v;
}

// QKV GEMM, 256x128 tile, BK=32, 4 waves (2M x 2N), per-wave 128x64 output.
// A/B LDS K-panels XOR-swizzled (chunk ^= row&3) via pre-swizzled gld_lds
// source + XOR'd ds_read. Double-buffered, single barrier per K-step.
// Epilogue: bf16 scatter to qkv[part][bh][t][d] with RoPE on parts 0,1.
__global__ __launch_bounds__(256) void gemm_qkv(
    const unsigned short* __restrict__ A, const unsigned short* __restrict__ Bw,
    const float* __restrict__ bias, const float* __restrict__ fcg,
    unsigned short* __restrict__ Cout)
{
  const int K = 1024, N = 3072;
  __shared__ __align__(16) unsigned short As[2][256 * 32];
  __shared__ __align__(16) unsigned short Bs[2][128 * 32];
  const int tid = threadIdx.x;
  const int lane = tid & 63, wid = tid >> 6;
  const int g = lane >> 4, l4 = lane & 15;
  const int wr = wid >> 1, wc = wid & 1;
  // bijective XCD swizzle: grid 768 (%8==0), cpx=96
  const int swz = (blockIdx.x & 7) * 96 + (blockIdx.x >> 3);
  const int bx = swz % 24, by = swz / 24;
  const int brow = by * 256, bcol = bx * 128;

  // staging geometry: A 4 chunks/thread, B 2 chunks/thread (16B each)
  int arow[4], acsc[4];
#pragma unroll
  for (int s = 0; s < 4; s++) {
    int c = tid + 256 * s;
    arow[s] = c >> 2;
    acsc[s] = (c & 3) ^ (arow[s] & 3);
  }
  int brow_[2], bcsc[2];
#pragma unroll
  for (int s = 0; s < 2; s++) {
    int c = tid + 256 * s;
    brow_[s] = c >> 2;
    bcsc[s] = (c & 3) ^ (brow_[s] & 3);
  }

  f32x4 acc[8][4] = {};

  // Prologue: stage K-step 0 into buffer 0.
#pragma unroll
  for (int s = 0; s < 4; s++)
    gld_lds16(A + (size_t)(brow + arow[s]) * K + acsc[s] * 8, &As[0][(tid + 256 * s) * 8]);
#pragma unroll
  for (int s = 0; s < 2; s++)
    gld_lds16(Bw + (size_t)(bcol + brow_[s]) * K + bcsc[s] * 8, &Bs[0][(tid + 256 * s) * 8]);
  __syncthreads();

  const int nk = K >> 5;   // 32
  for (int kk = 0; kk < nk; kk++) {
    const int cur = kk & 1;
    if (kk + 1 < nk) {
      const int k0 = (kk + 1) << 5;
#pragma unroll
      for (int s = 0; s < 4; s++)
        gld_lds16(A + (size_t)(brow + arow[s]) * K + k0 + acsc[s] * 8, &As[cur ^ 1][(tid + 256 * s) * 8]);
#pragma unroll
      for (int s = 0; s < 2; s++)
        gld_lds16(Bw + (size_t)(bcol + brow_[s]) * K + k0 + bcsc[s] * 8, &Bs[cur ^ 1][(tid + 256 * s) * 8]);
    }
    bf16x8 af[8], bfr[4];
#pragma unroll
    for (int mf = 0; mf < 8; mf++) {
      const int r = wr * 128 + mf * 16 + l4;
      af[mf] = *(const bf16x8*)&As[cur][r * 32 + ((g * 8) ^ ((r & 3) * 8))];
    }
#pragma unroll
    for (int nf = 0; nf < 4; nf++) {
      const int r = wc * 64 + nf * 16 + l4;
      bfr[nf] = *(const bf16x8*)&Bs[cur][r * 32 + ((g * 8) ^ ((r & 3) * 8))];
    }
    __builtin_amdgcn_s_setprio(1);
#pragma unroll
    for (int mf = 0; mf < 8; mf++)
#pragma unroll
      for (int nf = 0; nf < 4; nf++)
        acc[mf][nf] = __builtin_amdgcn_mfma_f32_16x16x32_bf16(af[mf], bfr[nf], acc[mf][nf], 0, 0, 0);
    __builtin_amdgcn_s_setprio(0);
    __syncthreads();
  }

  // Epilogue: bias + RoPE (q,k) + scatter to qkv[part][bh][t][d].
#pragma unroll
  for (int mf = 0; mf < 8; mf++) {
    const int grow0 = brow + wr * 128 + mf * 16 + 4 * g;
#pragma unroll
    for (int nf = 0; nf < 4; nf++) {
      const int gcol = bcol + wc * 64 + nf * 16 + l4;
      const float bv = bias[gcol];
      const int part = gcol >> 10;
      const int c = gcol & 1023;
      const int h = c >> 6, d = c & 63;
      const int dbase = d & ~1;
      const float sgn = (d & 1) ? 1.f : -1.f;
      const bool isqk = (part < 2);
#pragma unroll
      for (int r = 0; r < 4; r++) {
        const int grow = grow0 + r;
        const int b = grow >> 11, t = grow & 2047;
        float v = acc[mf][nf][r] + bv;
        float w = __shfl_xor(v, 1, 64);
        float o = v;
        if (isqk) {
          float cth = fcg[(size_t)t * 64 + dbase];
          float sth = fcg[(size_t)t * 64 + dbase + 1];
          o = v * cth + sgn * w * sth;
        }
        size_t dst = (size_t)part * ((size_t)BHX * TB * HD)
                   + ((size_t)(b * NH + h) * TB + t) * HD + d;
        Cout[dst] = bfb(o);
      }
    }
  }
}

// Projection GEMM: 128x128 tile, dbuf, f32 output + bias. (round-12 kernel)
__global__ __launch_bounds__(256) void gemm_proj(
    const unsigned short* __restrict__ A, const unsigned short* __restrict__ Bw,
    const float* __restrict__ bias, float* __restrict__ Cout)
{
  const int K = 1024, N = 1024;
  __shared__ __align__(16) unsigned short As[2][4096];
  __shared__ __align__(16) unsigned short Bs[2][4096];
  int tid = threadIdx.x;
  int lane = tid & 63, wid = tid >> 6;
  int g = lane >> 4, l4 = lane & 15;
  int wr = wid >> 1, wc = wid & 1;
  const int swz = (blockIdx.x & 7) * 64 + (blockIdx.x >> 3);
  const int bx = swz % 8, by = swz / 8;
  const int brow = by * 128, bcol = bx * 128;

  const unsigned short* ap = A + (size_t)(brow + (tid >> 2)) * K + (tid & 3) * 8;
  const unsigned short* bp_ = Bw + (size_t)(bcol + (tid >> 2)) * K + (tid & 3) * 8;
  const size_t rstep = (size_t)64 * K;
  const int lo = tid * 8;

  f32x4 acc[4][4] = {};

  gld_lds16(ap,          &As[0][lo]);
  gld_lds16(ap + rstep,  &As[0][lo + 2048]);
  gld_lds16(bp_,         &Bs[0][lo]);
  gld_lds16(bp_ + rstep, &Bs[0][lo + 2048]);
  ap += 32; bp_ += 32;
  __syncthreads();

  const int nk = K >> 5;
  for (int kk = 0; kk < nk; kk++) {
    const int cur = kk & 1;
    if (kk + 1 < nk) {
      gld_lds16(ap,          &As[cur ^ 1][lo]);
      gld_lds16(ap + rstep,  &As[cur ^ 1][lo + 2048]);
      gld_lds16(bp_,         &Bs[cur ^ 1][lo]);
      gld_lds16(bp_ + rstep, &Bs[cur ^ 1][lo + 2048]);
      ap += 32; bp_ += 32;
    }
    bf16x8 af[4], bfr[4];
#pragma unroll
    for (int i = 0; i < 4; i++)
      af[i] = *(const bf16x8*)&As[cur][(wr * 64 + i * 16 + l4) * 32 + g * 8];
#pragma unroll
    for (int i = 0; i < 4; i++)
      bfr[i] = *(const bf16x8*)&Bs[cur][(wc * 64 + i * 16 + l4) * 32 + g * 8];
    __builtin_amdgcn_s_setprio(1);
#pragma unroll
    for (int i = 0; i < 4; i++)
#pragma unroll
      for (int j = 0; j < 4; j++)
        acc[i][j] = __builtin_amdgcn_mfma_f32_16x16x32_bf16(af[i], bfr[j], acc[i][j], 0, 0, 0);
    __builtin_amdgcn_s_setprio(0);
    __syncthreads();
  }

#pragma unroll
  for (int i = 0; i < 4; i++) {
    int grow0 = brow + wr * 64 + i * 16 + 4 * g;
#pragma unroll
    for (int j = 0; j < 4; j++) {
      int gcol = bcol + wc * 64 + j * 16 + l4;
      float bv = bias[gcol];
#pragma unroll
      for (int r = 0; r < 4; r++)
        Cout[(size_t)(grow0 + r) * N + gcol] = acc[i][j][r] + bv;
    }
  }
}

// v [bh][T][64] -> vT [bh][64][T], 64x64 tiles. 256 threads, 2 chunks each way.
__global__ void transpose_v(const unsigned short* __restrict__ v,
                            unsigned short* __restrict__ vT) {
  int bh = blockIdx.y, t0 = blockIdx.x * 64;
  __shared__ __align__(16) unsigned short tile[64][72];
  int tid = threadIdx.x;
#pragma unroll
  for (int s = 0; s < 2; s++) {
    int cid = tid + 256 * s;
    int r = cid >> 3, c8 = (cid & 7) * 8;
    bf16x8 val = *(const bf16x8*)(v + ((size_t)bh * TB + t0 + r) * HD + c8);
    *(bf16x8*)&tile[r][c8] = val;
  }
  __syncthreads();
#pragma unroll
  for (int s = 0; s < 2; s++) {
    int cid = tid + 256 * s;
    int rr = cid >> 3, cc = (cid & 7) * 8;
    bf16x8 o;
#pragma unroll
    for (int i = 0; i < 8; i++) o[i] = (short)tile[cc + i][rr];
    *(bf16x8*)(vT + ((size_t)bh * HD + rr) * TB + t0 + cc) = o;
  }
}

// Flash attention fwd, causal. STATIC XCD-affine schedule (round-11 kernel).
__global__ __launch_bounds__(256, 4) void flash_fwd(
    const unsigned short* __restrict__ q, const unsigned short* __restrict__ k,
    const unsigned short* __restrict__ vT, unsigned short* __restrict__ yb)
{
  __shared__ __align__(16) unsigned short Ks[2][4096];
  __shared__ __align__(16) unsigned short Vs[2][4096];
  __shared__ __align__(16) unsigned short Ps[4][16][64];

  const int tid = threadIdx.x, wid = tid >> 6, lane = tid & 63;
  const int g = lane >> 4, l4 = lane & 15;

  const int b = blockIdx.x;
  const int xcd = b & 7;
  const int idx = b >> 3;
  const int bh = (xcd << 3) | (idx & 7);
  const int p = idx >> 3;

  const int off0 = tid << 4;
  const int row0 = off0 >> 7, sc0 = ((off0 >> 4) & 7) ^ (row0 & 7);
  const int off1 = off0 + 4096;
  const int row1 = off1 >> 7, sc1 = ((off1 >> 4) & 7) ^ (row1 & 7);
  const int koff0 = (row0 << 6) + (sc0 << 3);
  const int koff1 = (row1 << 6) + (sc1 << 3);
  const int voff0 = (row0 << 11) + (sc0 << 3);
  const int voff1 = (row1 << 11) + (sc1 << 3);

  const float SCL2 = 0.18033688011112042f;  // 1/8 * log2(e)

  const unsigned short* kb = k  + ((size_t)bh << 17);
  const unsigned short* vb = vT + ((size_t)bh << 17);

#pragma unroll 1
  for (int sel = 0; sel < 2; sel++) {
    const int q64 = sel ? (31 - p) : p;
    const int rbase = q64 * 64 + wid * 16;

    bf16x8 qf0, qf1;
    {
      const unsigned short* qp = q + (((size_t)bh * TB + rbase + l4) << 6);
      qf0 = *(const bf16x8*)(qp + g * 8);
      qf1 = *(const bf16x8*)(qp + 32 + g * 8);
    }

    float m_run[4], l_run[4];
    f32x4 acc_o[4] = {};
#pragma unroll
    for (int j = 0; j < 4; j++) { m_run[j] = -1e30f; l_run[j] = 0.f; }

    gld_lds16(kb + koff0, &Ks[0][off0 >> 1]);
    gld_lds16(kb + koff1, &Ks[0][off1 >> 1]);
    gld_lds16(vb + voff0, &Vs[0][off0 >> 1]);
    gld_lds16(vb + voff1, &Vs[0][off1 >> 1]);
    __syncthreads();

    for (int kt = 0; kt <= q64; kt++) {
      const int cur = kt & 1;
      if (kt < q64) {
        const int kadd = (kt + 1) << 12;
        const int vadd = (kt + 1) << 6;
        gld_lds16(kb + koff0 + kadd, &Ks[cur ^ 1][off0 >> 1]);
        gld_lds16(kb + koff1 + kadd, &Ks[cur ^ 1][off1 >> 1]);
        gld_lds16(vb + voff0 + vadd, &Vs[cur ^ 1][off0 >> 1]);
        gld_lds16(vb + voff1 + vadd, &Vs[cur ^ 1][off1 >> 1]);
      }
      const unsigned short* Kc = Ks[cur];
      const unsigned short* Vc = Vs[cur];

      float sv[4][4];
      __builtin_amdgcn_s_setprio(1);
#pragma unroll
      for (int cb = 0; cb < 4; cb++) {
        const int r = cb * 16 + l4;
        const int sw = (r & 7) * 8;
        bf16x8 kb0 = *(const bf16x8*)&Kc[r * 64 + ((g * 8) ^ sw)];
        bf16x8 kb1 = *(const bf16x8*)&Kc[r * 64 + (((g + 4) * 8) ^ sw)];
        f32x4 z = {0.f, 0.f, 0.f, 0.f};
        z = __builtin_amdgcn_mfma_f32_16x16x32_bf16(qf0, kb0, z, 0, 0, 0);
        z = __builtin_amdgcn_mfma_f32_16x16x32_bf16(qf1, kb1, z, 0, 0, 0);
#pragma unroll
        for (int j = 0; j < 4; j++)
          sv[cb][j] = z[j] * SCL2;
      }
      __builtin_amdgcn_s_setprio(0);
      if (kt == q64) {
        const int rq = wid * 16 + 4 * g;
#pragma unroll
        for (int cb = 0; cb < 4; cb++)
#pragma unroll
          for (int j = 0; j < 4; j++)
            if (cb * 16 + l4 > rq + j) sv[cb][j] = -1e30f;
      }

      float mt[4];
#pragma unroll
      for (int j = 0; j < 4; j++) {
        float m = fmaxf(fmaxf(sv[0][j], sv[1][j]), fmaxf(sv[2][j], sv[3][j]));
        m = fmaxf(m, dppf<0x121>(m));
        m = fmaxf(m, dppf<0x122>(m));
        m = fmaxf(m, dppf<0x124>(m));
        m = fmaxf(m, dppf<0x128>(m));
        mt[j] = m;
      }
      bool need = !((mt[0] <= m_run[0] + 8.f) & (mt[1] <= m_run[1] + 8.f) &
                    (mt[2] <= m_run[2] + 8.f) & (mt[3] <= m_run[3] + 8.f));
      if (__any(need)) {
#pragma unroll
        for (int j = 0; j < 4; j++) {
          float mn = fmaxf(m_run[j], mt[j]);
          float alpha = fexp2(m_run[j] - mn);
          m_run[j] = mn;
          l_run[j] *= alpha;
#pragma unroll
          for (int db = 0; db < 4; db++) acc_o[db][j] *= alpha;
        }
      }
#pragma unroll
      for (int j = 0; j < 4; j++) {
        float s0 = fexp2(sv[0][j] - m_run[j]); sv[0][j] = s0;
        float s1 = fexp2(sv[1][j] - m_run[j]); sv[1][j] = s1;
        float s2 = fexp2(sv[2][j] - m_run[j]); sv[2][j] = s2;
        float s3 = fexp2(sv[3][j] - m_run[j]); sv[3][j] = s3;
        float p2 = (s0 + s1) + (s2 + s3);
        p2 += dppf<0x121>(p2);
        p2 += dppf<0x122>(p2);
        p2 += dppf<0x124>(p2);
        p2 += dppf<0x128>(p2);
        l_run[j] += p2;
      }

#pragma unroll
      for (int cb = 0; cb < 4; cb++)
#pragma unroll
        for (int j = 0; j < 4; j++) {
          const int xch = (cb * 2 + (l4 >> 3)) ^ ((g & 1) * 4 + j);
          Ps[wid][4 * g + j][xch * 8 + (l4 & 7)] = bfb(sv[cb][j]);
        }
      asm volatile("s_waitcnt lgkmcnt(0)" ::: "memory");
      __builtin_amdgcn_sched_barrier(0);
      bf16x8 pa0 = *(const bf16x8*)&Ps[wid][l4][(g ^ (l4 & 7)) * 8];
      bf16x8 pa1 = *(const bf16x8*)&Ps[wid][l4][((4 + g) ^ (l4 & 7)) * 8];
      __builtin_amdgcn_s_setprio(1);
#pragma unroll
      for (int db = 0; db < 4; db++) {
        const int r = db * 16 + l4;
        const int sw = (r & 7) * 8;
        bf16x8 vb0 = *(const bf16x8*)&Vc[r * 64 + ((g * 8) ^ sw)];
        bf16x8 vb1 = *(const bf16x8*)&Vc[r * 64 + (((g + 4) * 8) ^ sw)];
        acc_o[db] = __builtin_amdgcn_mfma_f32_16x16x32_bf16(pa0, vb0, acc_o[db], 0, 0, 0);
        acc_o[db] = __builtin_amdgcn_mfma_f32_16x16x32_bf16(pa1, vb1, acc_o[db], 0, 0, 0);
      }
      __builtin_amdgcn_s_setprio(0);
      __syncthreads();
    }

    unsigned short* yp = yb + ((size_t)(bh >> 4) * TB) * CC + (size_t)(bh & 15) * HD;
    const int qr0 = rbase + 4 * g;
    float inv[4];
#pragma unroll
    for (int j = 0; j < 4; j++) inv[j] = 1.0f / l_run[j];
#pragma unroll
    for (int db = 0; db < 4; db++) {
      const int d = db * 16 + l4;
#pragma unroll
      for (int j = 0; j < 4; j++)
        yp[(size_t)(qr0 + j) * CC + d] = bfb(acc_o[db][j] * inv[j]);
    }
  }
}

extern "C" void kernel_launch(void* const* d_in, const int* in_sizes, int n_in,
                              void* d_out, int out_size, void* d_ws, size_t ws_size,
                              hipStream_t stream) {
  (void)in_sizes; (void)n_in; (void)out_size; (void)ws_size;
  const float* x  = (const float*)d_in[0];
  const float* fc = (const float*)d_in[1];
  // d_in[2]=attn_mask (tril), d_in[3]=padding_mask (all ones): applied analytically.
  const float* Wq = (const float*)d_in[4];
  const float* bq = (const float*)d_in[5];
  const float* Wk = (const float*)d_in[6];
  const float* bk = (const float*)d_in[7];
  const float* Wv = (const float*)d_in[8];
  const float* bv = (const float*)d_in[9];
  const float* Wp = (const float*)d_in[10];
  const float* bp = (const float*)d_in[11];

  char* ws = (char*)d_ws;
  unsigned short* xb   = (unsigned short*)(ws + 0);          // 8192x1024 bf16 (later reused as yb)
  unsigned short* wqkv = (unsigned short*)(ws + 16777216);   // 3072x1024 bf16
  unsigned short* wp   = (unsigned short*)(ws + 23068672);   // 1024x1024 bf16
  float*          bqkv = (float*)(ws + 25165824);            // 3072 f32
  unsigned short* qkv  = (unsigned short*)(ws + 25182208);   // 3 x [64][2048][64] bf16
  unsigned short* vT   = qkv + 3 * (size_t)8388608;          // [64][64][2048] bf16
  unsigned short* yb   = xb;

  cvt_f32_bf16<<<(2097152 + 255) / 256, 256, 0, stream>>>(x, xb, 2097152);
  cvt_w4<<<dim3(1024, 4), 256, 0, stream>>>(Wq, Wk, Wv, Wp,
      wqkv, wqkv + 1048576, wqkv + 2097152, wp);
  prep_bias<<<dim3(12), 256, 0, stream>>>(bq, bk, bv, bqkv);

  gemm_qkv<<<dim3(768), 256, 0, stream>>>(xb, wqkv, bqkv, fc, qkv);
  transpose_v<<<dim3(32, 64), 256, 0, stream>>>(qkv + 2 * (size_t)8388608, vT);
  flash_fwd<<<dim3(1024), 256, 0, stream>>>(qkv, qkv + (size_t)8388608, vT, yb);
  gemm_proj<<<dim3(512), 256, 0, stream>>>(yb, wp, bp, (float*)d_out);
}

// Round 14
// 220.702 us; speedup vs baseline: 1.1792x; 1.1792x over previous
//
#include <hip/hip_runtime.h>
#include <hip/hip_bf16.h>

#define TB 2048
#define CC 1024
#define NH 16
#define HD 64
#define NB 4
#define BHX (NB*NH)    // 64
#define BTX (NB*TB)    // 8192

typedef __attribute__((ext_vector_type(8))) short bf16x8;
typedef __attribute__((ext_vector_type(4))) float f32x4;
typedef __attribute__((ext_vector_type(4))) unsigned short us4;

__device__ __forceinline__ unsigned short bfb(float f) {
  __hip_bfloat16 h = __float2bfloat16(f);
  return __builtin_bit_cast(unsigned short, h);
}
__device__ __forceinline__ float fexp2(float x) {
  return __builtin_amdgcn_exp2f(x);   // v_exp_f32 (2^x)
}
template <int CTRL>
__device__ __forceinline__ float dppf(float x) {
  int r = __builtin_amdgcn_update_dpp(0, __builtin_bit_cast(int, x), CTRL, 0xf, 0xf, false);
  return __builtin_bit_cast(float, r);
}

__device__ __forceinline__ void gld_lds16(const void* g, void* l) {
  __builtin_amdgcn_global_load_lds(
      (const __attribute__((address_space(1))) unsigned*)g,
      (__attribute__((address_space(3))) unsigned*)l, 16, 0, 0);
}

__global__ void cvt_f32_bf16(const float* __restrict__ src,
                             unsigned short* __restrict__ dst, int n4) {
  int i = blockIdx.x * blockDim.x + threadIdx.x;
  if (i >= n4) return;
  f32x4 v = ((const f32x4*)src)[i];
  us4 o;
#pragma unroll
  for (int j = 0; j < 4; j++) o[j] = bfb(v[j]);
  ((us4*)dst)[i] = o;
}

// 4 weight matrices (1024x1024 f32 each) -> bf16, one launch.
__global__ void cvt_w4(const float* __restrict__ s0, const float* __restrict__ s1,
                       const float* __restrict__ s2, const float* __restrict__ s3,
                       unsigned short* __restrict__ d0, unsigned short* __restrict__ d1,
                       unsigned short* __restrict__ d2, unsigned short* __restrict__ d3) {
  int y = blockIdx.y;
  const float* s = y == 0 ? s0 : y == 1 ? s1 : y == 2 ? s2 : s3;
  unsigned short* d = y == 0 ? d0 : y == 1 ? d1 : y == 2 ? d2 : d3;
  int i = blockIdx.x * 256 + threadIdx.x;
  f32x4 v = ((const f32x4*)s)[i];
  us4 o;
#pragma unroll
  for (int j = 0; j < 4; j++) o[j] = bfb(v[j]);
  ((us4*)d)[i] = o;
}

__global__ void prep_bias(const float* __restrict__ bq, const float* __restrict__ bk,
                          const float* __restrict__ bv, float* __restrict__ out) {
  int i = blockIdx.x * 256 + threadIdx.x;   // grid 12*256 = 3072
  float v = i < 1024 ? bq[i] : i < 2048 ? bk[i - 1024] : bv[i - 2048];
  out[i] = v;
}

// C[i][n] = sum_k A[i][k]*Bw[n][k] + bias[n].  128x128 tile, BK=32, dbuf,
// single barrier per step, bijective XCD swizzle.
// LDS tiles use a conflict-free XOR bijection: logical (row r, 16B-chunk g)
// lives at line = r>>1 (128B lines), slot = (((r&1)<<2)|g) ^ (line&7).
// Staging dest stays LINEAR (tid*8) with inverse-mapped global source
// (rule #21); fragment reads use precomputed swizzled offsets. Per 16-lane
// read group each slot is hit exactly twice on different lines -> 2-way
// (free, m136) instead of the old 8-way.
// MODE 0: f32 output row-major [M][N]. MODE 1: bf16 scatter to
// qkv[part][bh][t][d] with RoPE on parts 0,1 via shfl partner exchange.
template <int MODE>
__global__ __launch_bounds__(256) void gemm_bt(
    const unsigned short* __restrict__ A, const unsigned short* __restrict__ Bw,
    const float* __restrict__ bias, const float* __restrict__ fcg,
    void* __restrict__ Cout, int M, int N, int K, int nbx)
{
  __shared__ __align__(16) unsigned short As[2][4096];
  __shared__ __align__(16) unsigned short Bs[2][4096];
  int tid = threadIdx.x;
  int lane = tid & 63, wid = tid >> 6;
  int g = lane >> 4, l4 = lane & 15;
  int wr = wid >> 1, wc = wid & 1;
  const int cpx = gridDim.x >> 3;
  const int swz = (blockIdx.x & 7) * cpx + (blockIdx.x >> 3);
  const int bx = swz % nbx, by = swz / nbx;
  const int brow = by * 128, bcol = bx * 128;

  // staging source (row, chunk) for linear dest chunks tid and tid+256
  const int s0 = (tid & 7) ^ ((tid >> 3) & 7);
  const int r0 = ((tid >> 3) << 1) | (s0 >> 2), g0 = s0 & 3;
  const int c1 = tid + 256;
  const int s1 = (c1 & 7) ^ ((c1 >> 3) & 7);
  const int r1 = ((c1 >> 3) << 1) | (s1 >> 2), g1 = s1 & 3;

  const unsigned short* a0 = A + (size_t)(brow + r0) * K + g0 * 8;
  const unsigned short* a1 = A + (size_t)(brow + r1) * K + g1 * 8;
  const unsigned short* b0 = Bw + (size_t)(bcol + r0) * K + g0 * 8;
  const unsigned short* b1 = Bw + (size_t)(bcol + r1) * K + g1 * 8;
  const int lo = tid * 8;

  // fragment read offsets (loop-invariant, swizzled)
  int aoff[4], boff[4];
#pragma unroll
  for (int i = 0; i < 4; i++) {
    int ra = wr * 64 + i * 16 + l4;
    aoff[i] = (ra >> 1) * 64 + (((((ra & 1) << 2) | g) ^ ((ra >> 1) & 7)) * 8);
    int rb = wc * 64 + i * 16 + l4;
    boff[i] = (rb >> 1) * 64 + (((((rb & 1) << 2) | g) ^ ((rb >> 1) & 7)) * 8);
  }

  f32x4 acc[4][4] = {};

  // Prologue: stage K-step 0 into buffer 0.
  gld_lds16(a0, &As[0][lo]);
  gld_lds16(a1, &As[0][lo + 2048]);
  gld_lds16(b0, &Bs[0][lo]);
  gld_lds16(b1, &Bs[0][lo + 2048]);
  a0 += 32; a1 += 32; b0 += 32; b1 += 32;
  __syncthreads();   // auto vmcnt(0): buf0 ready

  const int nk = K >> 5;
  for (int kk = 0; kk < nk; kk++) {
    const int cur = kk & 1;
    if (kk + 1 < nk) {   // issue next step's loads; they fly during compute
      gld_lds16(a0, &As[cur ^ 1][lo]);
      gld_lds16(a1, &As[cur ^ 1][lo + 2048]);
      gld_lds16(b0, &Bs[cur ^ 1][lo]);
      gld_lds16(b1, &Bs[cur ^ 1][lo + 2048]);
      a0 += 32; a1 += 32; b0 += 32; b1 += 32;
    }
    bf16x8 af[4], bfr[4];
#pragma unroll
    for (int i = 0; i < 4; i++)
      af[i] = *(const bf16x8*)&As[cur][aoff[i]];
#pragma unroll
    for (int i = 0; i < 4; i++)
      bfr[i] = *(const bf16x8*)&Bs[cur][boff[i]];
    __builtin_amdgcn_s_setprio(1);
#pragma unroll
    for (int i = 0; i < 4; i++)
#pragma unroll
      for (int j = 0; j < 4; j++)
        acc[i][j] = __builtin_amdgcn_mfma_f32_16x16x32_bf16(af[i], bfr[j], acc[i][j], 0, 0, 0);
    __builtin_amdgcn_s_setprio(0);
    __syncthreads();
  }

#pragma unroll
  for (int i = 0; i < 4; i++) {
    int grow0 = brow + wr * 64 + i * 16 + 4 * g;
#pragma unroll
    for (int j = 0; j < 4; j++) {
      int gcol = bcol + wc * 64 + j * 16 + l4;
      float bv = bias[gcol];
      if (MODE == 0) {
        float* out = (float*)Cout;
#pragma unroll
        for (int r = 0; r < 4; r++)
          out[(size_t)(grow0 + r) * N + gcol] = acc[i][j][r] + bv;
      } else {
        unsigned short* out = (unsigned short*)Cout;
        int part = gcol >> 10;
        int c = gcol & 1023;
        int h = c >> 6, d = c & 63;
        int dbase = d & ~1;
        float sgn = (d & 1) ? 1.f : -1.f;
        bool isqk = (part < 2);   // uniform across the l4/l4^1 pair
#pragma unroll
        for (int r = 0; r < 4; r++) {
          int grow = grow0 + r;
          int b = grow >> 11, t = grow & 2047;
          float v = acc[i][j][r] + bv;
          float w = __shfl_xor(v, 1, 64);  // partner dim's value
          float o = v;
          if (isqk) {
            float cth = fcg[(size_t)t * 64 + dbase];
            float sth = fcg[(size_t)t * 64 + dbase + 1];
            o = v * cth + sgn * w * sth;
          }
          size_t dst = (size_t)part * ((size_t)BHX * TB * HD)
                     + ((size_t)(b * NH + h) * TB + t) * HD + d;
          out[dst] = bfb(o);
        }
      }
    }
  }
}

// v [bh][T][64] -> vT [bh][64][T], 64x64 tiles. 256 threads, 2 chunks each way.
__global__ void transpose_v(const unsigned short* __restrict__ v,
                            unsigned short* __restrict__ vT) {
  int bh = blockIdx.y, t0 = blockIdx.x * 64;
  __shared__ __align__(16) unsigned short tile[64][72];
  int tid = threadIdx.x;
#pragma unroll
  for (int s = 0; s < 2; s++) {
    int cid = tid + 256 * s;
    int r = cid >> 3, c8 = (cid & 7) * 8;
    bf16x8 val = *(const bf16x8*)(v + ((size_t)bh * TB + t0 + r) * HD + c8);
    *(bf16x8*)&tile[r][c8] = val;
  }
  __syncthreads();
#pragma unroll
  for (int s = 0; s < 2; s++) {
    int cid = tid + 256 * s;
    int rr = cid >> 3, cc = (cid & 7) * 8;
    bf16x8 o;
#pragma unroll
    for (int i = 0; i < 8; i++) o[i] = (short)tile[cc + i][rr];
    *(bf16x8*)(vT + ((size_t)bh * HD + rr) * TB + t0 + cc) = o;
  }
}

// Flash attention fwd, causal. STATIC XCD-affine schedule (round-11 kernel).
__global__ __launch_bounds__(256, 4) void flash_fwd(
    const unsigned short* __restrict__ q, const unsigned short* __restrict__ k,
    const unsigned short* __restrict__ vT, unsigned short* __restrict__ yb)
{
  __shared__ __align__(16) unsigned short Ks[2][4096];
  __shared__ __align__(16) unsigned short Vs[2][4096];
  __shared__ __align__(16) unsigned short Ps[4][16][64];

  const int tid = threadIdx.x, wid = tid >> 6, lane = tid & 63;
  const int g = lane >> 4, l4 = lane & 15;

  const int b = blockIdx.x;
  const int xcd = b & 7;
  const int idx = b >> 3;
  const int bh = (xcd << 3) | (idx & 7);
  const int p = idx >> 3;

  const int off0 = tid << 4;
  const int row0 = off0 >> 7, sc0 = ((off0 >> 4) & 7) ^ (row0 & 7);
  const int off1 = off0 + 4096;
  const int row1 = off1 >> 7, sc1 = ((off1 >> 4) & 7) ^ (row1 & 7);
  const int koff0 = (row0 << 6) + (sc0 << 3);
  const int koff1 = (row1 << 6) + (sc1 << 3);
  const int voff0 = (row0 << 11) + (sc0 << 3);
  const int voff1 = (row1 << 11) + (sc1 << 3);

  const float SCL2 = 0.18033688011112042f;  // 1/8 * log2(e)

  const unsigned short* kb = k  + ((size_t)bh << 17);
  const unsigned short* vb = vT + ((size_t)bh << 17);

#pragma unroll 1
  for (int sel = 0; sel < 2; sel++) {
    const int q64 = sel ? (31 - p) : p;
    const int rbase = q64 * 64 + wid * 16;

    bf16x8 qf0, qf1;
    {
      const unsigned short* qp = q + (((size_t)bh * TB + rbase + l4) << 6);
      qf0 = *(const bf16x8*)(qp + g * 8);
      qf1 = *(const bf16x8*)(qp + 32 + g * 8);
    }

    float m_run[4], l_run[4];
    f32x4 acc_o[4] = {};
#pragma unroll
    for (int j = 0; j < 4; j++) { m_run[j] = -1e30f; l_run[j] = 0.f; }

    gld_lds16(kb + koff0, &Ks[0][off0 >> 1]);
    gld_lds16(kb + koff1, &Ks[0][off1 >> 1]);
    gld_lds16(vb + voff0, &Vs[0][off0 >> 1]);
    gld_lds16(vb + voff1, &Vs[0][off1 >> 1]);
    __syncthreads();

    for (int kt = 0; kt <= q64; kt++) {
      const int cur = kt & 1;
      if (kt < q64) {
        const int kadd = (kt + 1) << 12;
        const int vadd = (kt + 1) << 6;
        gld_lds16(kb + koff0 + kadd, &Ks[cur ^ 1][off0 >> 1]);
        gld_lds16(kb + koff1 + kadd, &Ks[cur ^ 1][off1 >> 1]);
        gld_lds16(vb + voff0 + vadd, &Vs[cur ^ 1][off0 >> 1]);
        gld_lds16(vb + voff1 + vadd, &Vs[cur ^ 1][off1 >> 1]);
      }
      const unsigned short* Kc = Ks[cur];
      const unsigned short* Vc = Vs[cur];

      float sv[4][4];
      __builtin_amdgcn_s_setprio(1);
#pragma unroll
      for (int cb = 0; cb < 4; cb++) {
        const int r = cb * 16 + l4;
        const int sw = (r & 7) * 8;
        bf16x8 kb0 = *(const bf16x8*)&Kc[r * 64 + ((g * 8) ^ sw)];
        bf16x8 kb1 = *(const bf16x8*)&Kc[r * 64 + (((g + 4) * 8) ^ sw)];
        f32x4 z = {0.f, 0.f, 0.f, 0.f};
        z = __builtin_amdgcn_mfma_f32_16x16x32_bf16(qf0, kb0, z, 0, 0, 0);
        z = __builtin_amdgcn_mfma_f32_16x16x32_bf16(qf1, kb1, z, 0, 0, 0);
#pragma unroll
        for (int j = 0; j < 4; j++)
          sv[cb][j] = z[j] * SCL2;
      }
      __builtin_amdgcn_s_setprio(0);
      if (kt == q64) {
        const int rq = wid * 16 + 4 * g;
#pragma unroll
        for (int cb = 0; cb < 4; cb++)
#pragma unroll
          for (int j = 0; j < 4; j++)
            if (cb * 16 + l4 > rq + j) sv[cb][j] = -1e30f;
      }

      float mt[4];
#pragma unroll
      for (int j = 0; j < 4; j++) {
        float m = fmaxf(fmaxf(sv[0][j], sv[1][j]), fmaxf(sv[2][j], sv[3][j]));
        m = fmaxf(m, dppf<0x121>(m));
        m = fmaxf(m, dppf<0x122>(m));
        m = fmaxf(m, dppf<0x124>(m));
        m = fmaxf(m, dppf<0x128>(m));
        mt[j] = m;
      }
      bool need = !((mt[0] <= m_run[0] + 8.f) & (mt[1] <= m_run[1] + 8.f) &
                    (mt[2] <= m_run[2] + 8.f) & (mt[3] <= m_run[3] + 8.f));
      if (__any(need)) {
#pragma unroll
        for (int j = 0; j < 4; j++) {
          float mn = fmaxf(m_run[j], mt[j]);
          float alpha = fexp2(m_run[j] - mn);
          m_run[j] = mn;
          l_run[j] *= alpha;
#pragma unroll
          for (int db = 0; db < 4; db++) acc_o[db][j] *= alpha;
        }
      }
#pragma unroll
      for (int j = 0; j < 4; j++) {
        float s0 = fexp2(sv[0][j] - m_run[j]); sv[0][j] = s0;
        float s1 = fexp2(sv[1][j] - m_run[j]); sv[1][j] = s1;
        float s2 = fexp2(sv[2][j] - m_run[j]); sv[2][j] = s2;
        float s3 = fexp2(sv[3][j] - m_run[j]); sv[3][j] = s3;
        float p2 = (s0 + s1) + (s2 + s3);
        p2 += dppf<0x121>(p2);
        p2 += dppf<0x122>(p2);
        p2 += dppf<0x124>(p2);
        p2 += dppf<0x128>(p2);
        l_run[j] += p2;
      }

#pragma unroll
      for (int cb = 0; cb < 4; cb++)
#pragma unroll
        for (int j = 0; j < 4; j++) {
          const int xch = (cb * 2 + (l4 >> 3)) ^ ((g & 1) * 4 + j);
          Ps[wid][4 * g + j][xch * 8 + (l4 & 7)] = bfb(sv[cb][j]);
        }
      asm volatile("s_waitcnt lgkmcnt(0)" ::: "memory");
      __builtin_amdgcn_sched_barrier(0);
      bf16x8 pa0 = *(const bf16x8*)&Ps[wid][l4][(g ^ (l4 & 7)) * 8];
      bf16x8 pa1 = *(const bf16x8*)&Ps[wid][l4][((4 + g) ^ (l4 & 7)) * 8];
      __builtin_amdgcn_s_setprio(1);
#pragma unroll
      for (int db = 0; db < 4; db++) {
        const int r = db * 16 + l4;
        const int sw = (r & 7) * 8;
        bf16x8 vb0 = *(const bf16x8*)&Vc[r * 64 + ((g * 8) ^ sw)];
        bf16x8 vb1 = *(const bf16x8*)&Vc[r * 64 + (((g + 4) * 8) ^ sw)];
        acc_o[db] = __builtin_amdgcn_mfma_f32_16x16x32_bf16(pa0, vb0, acc_o[db], 0, 0, 0);
        acc_o[db] = __builtin_amdgcn_mfma_f32_16x16x32_bf16(pa1, vb1, acc_o[db], 0, 0, 0);
      }
      __builtin_amdgcn_s_setprio(0);
      __syncthreads();
    }

    unsigned short* yp = yb + ((size_t)(bh >> 4) * TB) * CC + (size_t)(bh & 15) * HD;
    const int qr0 = rbase + 4 * g;
    float inv[4];
#pragma unroll
    for (int j = 0; j < 4; j++) inv[j] = 1.0f / l_run[j];
#pragma unroll
    for (int db = 0; db < 4; db++) {
      const int d = db * 16 + l4;
#pragma unroll
      for (int j = 0; j < 4; j++)
        yp[(size_t)(qr0 + j) * CC + d] = bfb(acc_o[db][j] * inv[j]);
    }
  }
}

extern "C" void kernel_launch(void* const* d_in, const int* in_sizes, int n_in,
                              void* d_out, int out_size, void* d_ws, size_t ws_size,
                              hipStream_t stream) {
  (void)in_sizes; (void)n_in; (void)out_size; (void)ws_size;
  const float* x  = (const float*)d_in[0];
  const float* fc = (const float*)d_in[1];
  // d_in[2]=attn_mask (tril), d_in[3]=padding_mask (all ones): applied analytically.
  const float* Wq = (const float*)d_in[4];
  const float* bq = (const float*)d_in[5];
  const float* Wk = (const float*)d_in[6];
  const float* bk = (const float*)d_in[7];
  const float* Wv = (const float*)d_in[8];
  const float* bv = (const float*)d_in[9];
  const float* Wp = (const float*)d_in[10];
  const float* bp = (const float*)d_in[11];

  char* ws = (char*)d_ws;
  unsigned short* xb   = (unsigned short*)(ws + 0);          // 8192x1024 bf16 (later reused as yb)
  unsigned short* wqkv = (unsigned short*)(ws + 16777216);   // 3072x1024 bf16
  unsigned short* wp   = (unsigned short*)(ws + 23068672);   // 1024x1024 bf16
  float*          bqkv = (float*)(ws + 25165824);            // 3072 f32
  unsigned short* qkv  = (unsigned short*)(ws + 25182208);   // 3 x [64][2048][64] bf16
  unsigned short* vT   = qkv + 3 * (size_t)8388608;          // [64][64][2048] bf16
  unsigned short* yb   = xb;

  cvt_f32_bf16<<<(2097152 + 255) / 256, 256, 0, stream>>>(x, xb, 2097152);
  cvt_w4<<<dim3(1024, 4), 256, 0, stream>>>(Wq, Wk, Wv, Wp,
      wqkv, wqkv + 1048576, wqkv + 2097152, wp);
  prep_bias<<<dim3(12), 256, 0, stream>>>(bq, bk, bv, bqkv);

  gemm_bt<1><<<dim3(1536), 256, 0, stream>>>(xb, wqkv, bqkv, fc, qkv, BTX, 3072, 1024, 24);
  transpose_v<<<dim3(32, 64), 256, 0, stream>>>(qkv + 2 * (size_t)8388608, vT);
  flash_fwd<<<dim3(1024), 256, 0, stream>>>(qkv, qkv + (size_t)8388608, vT, yb);
  gemm_bt<0><<<dim3(512), 256, 0, stream>>>(yb, wp, bp, nullptr, (float*)d_out, BTX, 1024, 1024, 8);
}